// Round 10
// baseline (127.261 us; speedup 1.0000x reference)
//
#include <hip/hip_runtime.h>
#include <hip/hip_bf16.h>

// RuleNBFNet: B=8, D=64, H=3, R2=12, Rn=1728.  Inputs f32, output f32.
// 4-kernel pipeline: k_pre1 (Wt,relT,QW1) -> k_mid (Q2,QW3; in-block C2/C2W/P1)
// -> k_score (LDS-staged Wt2, 4 rules/wave, scores out) -> k_final (softmax+emb).
// Feature algebra: m=q*rel, p=max(m,0), n=min(m,0):
//   0.5m*W0 + p*W1 + n*W2 + max(0.5|m|,1e-3)*W3
//     = p*A + n*Bc + max(|m|,2e-3)*Wz'   with A=0.5W0+W1, Bc=0.5W0+W2, Wz'=0.5W3
// (bitwise-exact refold: pure exponent shifts; |m| via v_max abs-modifier -> 7 ops)
// Wt float4 (A,Bc,Wz',0) at [l][d][j]; scales_tail=[1,4/3,3/4] folded.
// std identity: sqrt(max(0.25m^2,eps)) == max(0.5|m|,1e-3) (exact).
// mlp_b2 softmax-invariant -> dropped.
// R8 lesson: cross-block atomic bins + last-block readback corrupted output
// (G16) -> separate k_final kept. R9: LDS-staged Wt2 works (124.8us).
// Harness floor: ~41us 256MiB poison-fill + ~50us memops per iteration.

typedef const float* fp;

// workspace layout (floats)
#define WS_WT     0        // 3*64*64*4 = 49152   Wt[l][d][j][c]
#define WS_RELT   49152    // 3*8*12*64 = 18432   relT[l][b][j][d]
#define WS_QW1    67584    // 8*64                query@mlp_W1[64:128]+mlp_b1
#define WS_Q2     68096    // 8*144*64 = 73728
#define WS_QW3    141824   // 8*12*64             Q3@lin_W2[0:64] + lin_b2
#define WS_SCORES 142592   // 8*1728
// total 156416 floats

__device__ __forceinline__ void acc4f(float q, float rv, float4 wv, float& acc){
  float m = q*rv;
  float p = fmaxf(m, 0.f), n = fminf(m, 0.f);
  acc += p*wv.x;
  acc += n*wv.y;
  acc += fmaxf(fabsf(m), 2e-3f)*wv.z;     // Wz pre-scaled by 0.5
}

__global__ void k_pre1(fp lin_W, fp query, fp rel_W, fp rel_b, fp mlp_W1,
                       fp mlp_b1, float* ws){
  int t = blockIdx.x*256 + threadIdx.x;
  if (t < 49152){
    // Wt[l][d][j][c]: t = l*16384 + d*256 + j*4 + c  (coalesced writes)
    int c = t & 3; int j = (t>>2)&63; int d = (t>>8)&63; int l = t>>14;
    fp W = lin_W + (size_t)l*832*64 + (64 + 12*d)*64 + j;   // rows stride 64
    float v = 0.f;
    if (c == 0){
      float w0 = W[0] + (4.f/3.f)*W[64]  + 0.75f*W[128];
      float w1 = W[192] + (4.f/3.f)*W[256] + 0.75f*W[320];
      v = 0.5f*w0 + w1;
    } else if (c == 1){
      float w0 = W[0] + (4.f/3.f)*W[64]  + 0.75f*W[128];
      float w2 = W[384] + (4.f/3.f)*W[448] + 0.75f*W[512];
      v = 0.5f*w0 + w2;
    } else if (c == 2){
      v = 0.5f*(W[576] + (4.f/3.f)*W[640] + 0.75f*W[704]);  // Wz' = 0.5*Wz
    }
    ws[WS_WT + t] = v;
  } else if (t < 67584){
    // relT[l][b][j][d] = (query[b] @ rel_W[l])[j*64+d] + rel_b[l][j*64+d]
    int e = t - 49152;
    int d = e & 63; int j = (e>>6)%12; int b = (e/768)&7; int l = e/6144;
    float acc = rel_b[l*768 + j*64 + d];
    fp W = rel_W + (size_t)l*64*768 + j*64 + d;
    fp q = query + b*64;
    #pragma unroll 8
    for (int k=0;k<64;k++) acc += q[k] * W[k*768];
    ws[WS_RELT + e] = acc;
  } else if (t < 68096){
    int e = t - 67584; int b = e>>6; int j = e&63;
    float acc = mlp_b1[j];
    fp q = query + b*64;
    #pragma unroll 8
    for (int i=0;i<64;i++) acc += q[i] * mlp_W1[(64+i)*64 + j];
    ws[WS_QW1 + e] = acc;
  }
}

// blocks 0..95: (b,i0) -> Q2[b,i0,0..11]; blocks 96..103: b -> QW3[b,0..11]
__global__ void k_mid(fp indicator, fp lin_W, fp lin_b, float* ws){
  __shared__ float sC2[64], sC2W[64], sP1[64], sQ3[12][64];
  int tid = threadIdx.x;                    // 768 threads = 12 waves
  int w = tid>>6, j = tid&63;
  bool isQ2 = blockIdx.x < 96;
  int b  = isQ2 ? blockIdx.x/12 : blockIdx.x-96;
  int i0 = isQ2 ? blockIdx.x%12 : 0;
  if (w == 0){
    float acc = lin_b[j];                   // C2: layer0 const state
    #pragma unroll 8
    for (int d=0; d<64; d++) acc += 2e-3f * ws[WS_WT + ((d<<6)+j)*4 + 2];
    sC2[j] = fmaxf(acc, 0.f);               // 2e-3*Wz' == 1e-3*Wz (exact)
  } else if (w == 1 && isQ2){
    const float4* W4 = (const float4*)(ws + WS_WT);        // layer0 Wt
    const float* rel = ws + WS_RELT + (b*12+i0)*64;        // l=0
    float acc = lin_b[j];
    #pragma unroll 4
    for (int d=0; d<64; d++) acc4f(indicator[d], rel[d], W4[(d<<6)+j], acc);
    sP1[j] = fmaxf(acc, 0.f);
  }
  __syncthreads();
  if (w == 0){
    float a2 = lin_b[64+j];                 // C2W = C2 @ lin_W1[0:64] + b1
    fp W1 = lin_W + 832*64;
    #pragma unroll 8
    for (int k=0;k<64;k++) a2 += sC2[k] * W1[k*64+j];
    sC2W[j] = a2;
  }
  __syncthreads();
  const float4* W4 = (const float4*)(ws + WS_WT + 16384);  // layer1 Wt
  const float* rel = ws + WS_RELT + 6144 + (b*12+w)*64;    // l=1, idx=w
  if (isQ2){
    float acc = sC2W[j];
    #pragma unroll 4
    for (int d=0; d<64; d++) acc4f(sP1[d], rel[d], W4[(d<<6)+j], acc);
    ws[WS_Q2 + ((b*12+i0)*12+w)*64 + j] = fmaxf(acc, 0.f);
  } else {
    float acc = sC2W[j];
    #pragma unroll 4
    for (int d=0; d<64; d++) acc4f(sC2[d], rel[d], W4[(d<<6)+j], acc);
    sQ3[w][j] = fmaxf(acc, 0.f);
    __syncthreads();                        // block-uniform branch
    fp W2 = lin_W + 2*832*64;               // layer2, rows 0..63
    float a = lin_b[128+j];
    #pragma unroll 8
    for (int k=0;k<64;k++) a += sQ3[w][k]*W2[k*64+j];
    ws[WS_QW3 + (b*12+w)*64 + j] = a;
  }
}

// 864 blocks x 256 thr; wave = 4 rules (b,i0,i2 shared, i1 = i1b..i1b+3).
// Wt2 staged through LDS in 2x32KB chunks (fewer barriers than 4x16KB).
__global__ __launch_bounds__(256) void k_score(fp mlp_W1, fp mlp_W2, float* ws){
  __shared__ float wt_s[8192];              // 32 KB chunk
  __shared__ float fin[4][4][64];
  int tid = threadIdx.x, w = tid>>6, j = tid&63;
  int wave = blockIdx.x*4 + w;              // 0..3455
  int b = blockIdx.x/108;                   // block-uniform (432 waves/b)
  int rem = wave%432;
  int i0 = rem/36; int t36 = rem%36;
  int i2 = t36/3;  int i1b = (t36%3)*4;
  const float4* relv = (const float4*)(ws + WS_RELT + 12288 + (b*12+i2)*64);
  const float* q2base = ws + WS_Q2 + ((b*12+i0)*12 + i1b)*64;
  const float4* q0v = (const float4*)(q2base);
  const float4* q1v = (const float4*)(q2base + 64);
  const float4* q2v = (const float4*)(q2base + 128);
  const float4* q3v = (const float4*)(q2base + 192);
  float a0 = ws[WS_QW3 + (b*12+i2)*64 + j];
  float acc0=a0, acc1=a0, acc2=a0, acc3=a0;
  const float4* Wt2 = (const float4*)(ws + WS_WT + 32768);
  for (int ch=0; ch<2; ch++){
    __syncthreads();                        // protect previous chunk
    {
      const float4* src = Wt2 + ch*2048;
      float4* dst = (float4*)wt_s;
      #pragma unroll
      for (int k=0; k<8; k++) dst[tid + k*256] = src[tid + k*256];
    }
    __syncthreads();
    #pragma unroll
    for (int dq=0; dq<8; dq++){
      int dc = ch*8 + dq;
      float4 rv = relv[dc];
      float4 qa = q0v[dc], qb = q1v[dc], qc = q2v[dc], qd = q3v[dc];
      const float4* wl = (const float4*)wt_s + dq*256 + j;
      float4 w0 = wl[0], w1 = wl[64], w2 = wl[128], w3 = wl[192];
      acc4f(qa.x, rv.x, w0, acc0); acc4f(qb.x, rv.x, w0, acc1);
      acc4f(qc.x, rv.x, w0, acc2); acc4f(qd.x, rv.x, w0, acc3);
      acc4f(qa.y, rv.y, w1, acc0); acc4f(qb.y, rv.y, w1, acc1);
      acc4f(qc.y, rv.y, w1, acc2); acc4f(qd.y, rv.y, w1, acc3);
      acc4f(qa.z, rv.z, w2, acc0); acc4f(qb.z, rv.z, w2, acc1);
      acc4f(qc.z, rv.z, w2, acc2); acc4f(qd.z, rv.z, w2, acc3);
      acc4f(qa.w, rv.w, w3, acc0); acc4f(qb.w, rv.w, w3, acc1);
      acc4f(qc.w, rv.w, w3, acc2); acc4f(qd.w, rv.w, w3, acc3);
    }
  }
  __syncthreads();
  fin[w][0][j]=fmaxf(acc0,0.f); fin[w][1][j]=fmaxf(acc1,0.f);
  fin[w][2][j]=fmaxf(acc2,0.f); fin[w][3][j]=fmaxf(acc3,0.f);
  __syncthreads();
  float qw = ws[WS_QW1 + b*64 + j];
  float w2v = mlp_W2[j];
  float h0=qw, h1=qw, h2=qw, h3=qw;
  #pragma unroll 8
  for (int i=0;i<64;i++){
    float wv = mlp_W1[i*64+j];              // rows 0..63, shared by 4 rules
    h0 += fin[w][0][i]*wv; h1 += fin[w][1][i]*wv;
    h2 += fin[w][2][i]*wv; h3 += fin[w][3][i]*wv;
  }
  float s0=fmaxf(h0,0.f)*w2v, s1=fmaxf(h1,0.f)*w2v;
  float s2=fmaxf(h2,0.f)*w2v, s3=fmaxf(h3,0.f)*w2v;
  #pragma unroll
  for (int off=32; off>0; off>>=1){
    s0 += __shfl_down(s0, off, 64); s1 += __shfl_down(s1, off, 64);
    s2 += __shfl_down(s2, off, 64); s3 += __shfl_down(s3, off, 64);
  }
  if (j == 0){
    int rbase = i0*144 + i1b*12 + i2;
    float* S = ws + WS_SCORES + b*1728 + rbase;
    S[0] = s0; S[12] = s1; S[24] = s2; S[36] = s3;
  }
}

__global__ void k_final(fp relation_emb, float* ws, float* out){
  int b = blockIdx.x, tid = threadIdx.x;           // 256 threads
  __shared__ float se[1728];
  __shared__ float red[256];
  __shared__ float pb[36][4];
  __shared__ float bins[36];
  const float* sc = ws + WS_SCORES + b*1728;
  float mx = -1e30f;
  for (int r=tid; r<1728; r+=256){ float v = sc[r]; se[r] = v; mx = fmaxf(mx, v); }
  red[tid] = mx; __syncthreads();
  for (int s=128; s>0; s>>=1){ if (tid<s) red[tid] = fmaxf(red[tid], red[tid+s]); __syncthreads(); }
  mx = red[0]; __syncthreads();
  float ts = 0.f;
  for (int r=tid; r<1728; r+=256){ float e = __expf(se[r]-mx); se[r] = e; ts += e; }
  red[tid] = ts; __syncthreads();
  for (int s=128; s>0; s>>=1){ if (tid<s) red[tid] += red[tid+s]; __syncthreads(); }
  float tot = red[0]; __syncthreads();
  if (tid < 144){                           // 4 partials per bin
    int bin = tid>>2, q = tid&3;            // bin = h*12+jj
    int h = bin/12, jj = bin%12;
    float a = 0.f;
    if (h == 0){
      const float* p = se + jj*144 + q*36;
      #pragma unroll 4
      for (int k=0;k<36;k++) a += p[k];
    } else if (h == 1){
      for (int t=q*36; t<q*36+36; t++) a += se[(t/12)*144 + jj*12 + (t%12)];
    } else {
      for (int t=q*36; t<q*36+36; t++) a += se[(t/12)*144 + (t%12)*12 + jj];
    }
    pb[bin][q] = a;
  }
  __syncthreads();
  if (tid < 36) bins[tid] = (pb[tid][0]+pb[tid][1]) + (pb[tid][2]+pb[tid][3]);
  __syncthreads();
  if (tid < 192){
    int h = tid>>6, d = tid&63;
    float acc = 0.f;
    #pragma unroll
    for (int jj=0; jj<12; jj++) acc += bins[h*12+jj] * relation_emb[jj*64+d];
    out[b*192 + tid] = acc/tot;                    // subgoals, f32
  }
  if (tid >= 192 && tid < 195){
    out[1536 + b*3 + (tid-192)] = 1.0f;            // masks = True, f32
  }
}

extern "C" void kernel_launch(void* const* d_in, const int* in_sizes, int n_in,
                              void* d_out, int out_size, void* d_ws, size_t ws_size,
                              hipStream_t stream){
  fp query        = (fp)d_in[0];
  fp relation_emb = (fp)d_in[1];
  fp indicator    = (fp)d_in[2];
  fp rel_W        = (fp)d_in[3];
  fp rel_b        = (fp)d_in[4];
  fp lin_W        = (fp)d_in[5];
  fp lin_b        = (fp)d_in[6];
  fp mlp_W1       = (fp)d_in[7];
  fp mlp_b1       = (fp)d_in[8];
  fp mlp_W2       = (fp)d_in[9];
  float* ws = (float*)d_ws;
  float* out = (float*)d_out;

  k_pre1 <<<266, 256, 0, stream>>>(lin_W, query, rel_W, rel_b, mlp_W1, mlp_b1, ws);
  k_mid  <<<104, 768, 0, stream>>>(indicator, lin_W, lin_b, ws);
  k_score<<<864, 256, 0, stream>>>(mlp_W1, mlp_W2, ws);
  k_final<<<8,   256, 0, stream>>>(relation_emb, ws, out);
}

// Round 11
// 122.827 us; speedup vs baseline: 1.0361x; 1.0361x over previous
//
#include <hip/hip_runtime.h>
#include <hip/hip_bf16.h>

// RuleNBFNet: B=8, D=64, H=3, R2=12, Rn=1728.  Inputs f32, output f32.
// 4-kernel pipeline: k_pre1 (Wt,relT,QW1) -> k_mid (Q2,QW3; in-block C2/C2W/P1)
// -> k_score (LDS-staged Wt2, 4 rules/wave, scores out) -> k_final (softmax+emb).
// Feature algebra: m=q*rel, p=max(m,0), n=min(m,0):
//   0.5m*W0 + p*W1 + n*W2 + max(0.5|m|,1e-3)*W3
//     = p*A + n*Bc + max(|m|,2e-3)*Wz'   with A=0.5W0+W1, Bc=0.5W0+W2, Wz'=0.5W3
// (bitwise-exact refold: pure exponent shifts; |m| via v_max abs-modifier -> 7 ops)
// Wt float4 (A,Bc,Wz',0) at [l][d][j]; scales_tail=[1,4/3,3/4] folded.
// std identity: sqrt(max(0.25m^2,eps)) == max(0.5|m|,1e-3) (exact).
// mlp_b2 softmax-invariant -> dropped.
// R8 lesson: cross-block atomic bins + last-block readback corrupted output
// (G16) -> separate k_final kept.
// R10 lesson: 32KB LDS chunks (36KB/block) regressed vs 16KB (20KB/block) --
// scheduling slack beats barrier count at this grid size. 16KB restored.
// Harness floor: ~41us 256MiB poison-fill (at HBM ceiling) + ~50us memops/iter.

typedef const float* fp;

// workspace layout (floats)
#define WS_WT     0        // 3*64*64*4 = 49152   Wt[l][d][j][c]
#define WS_RELT   49152    // 3*8*12*64 = 18432   relT[l][b][j][d]
#define WS_QW1    67584    // 8*64                query@mlp_W1[64:128]+mlp_b1
#define WS_Q2     68096    // 8*144*64 = 73728
#define WS_QW3    141824   // 8*12*64             Q3@lin_W2[0:64] + lin_b2
#define WS_SCORES 142592   // 8*1728
// total 156416 floats

__device__ __forceinline__ void acc4f(float q, float rv, float4 wv, float& acc){
  float m = q*rv;
  float p = fmaxf(m, 0.f), n = fminf(m, 0.f);
  acc += p*wv.x;
  acc += n*wv.y;
  acc += fmaxf(fabsf(m), 2e-3f)*wv.z;     // Wz pre-scaled by 0.5
}

__global__ void k_pre1(fp lin_W, fp query, fp rel_W, fp rel_b, fp mlp_W1,
                       fp mlp_b1, float* ws){
  int t = blockIdx.x*256 + threadIdx.x;
  if (t < 49152){
    // Wt[l][d][j][c]: t = l*16384 + d*256 + j*4 + c  (coalesced writes)
    int c = t & 3; int j = (t>>2)&63; int d = (t>>8)&63; int l = t>>14;
    fp W = lin_W + (size_t)l*832*64 + (64 + 12*d)*64 + j;   // rows stride 64
    float v = 0.f;
    if (c == 0){
      float w0 = W[0] + (4.f/3.f)*W[64]  + 0.75f*W[128];
      float w1 = W[192] + (4.f/3.f)*W[256] + 0.75f*W[320];
      v = 0.5f*w0 + w1;
    } else if (c == 1){
      float w0 = W[0] + (4.f/3.f)*W[64]  + 0.75f*W[128];
      float w2 = W[384] + (4.f/3.f)*W[448] + 0.75f*W[512];
      v = 0.5f*w0 + w2;
    } else if (c == 2){
      v = 0.5f*(W[576] + (4.f/3.f)*W[640] + 0.75f*W[704]);  // Wz' = 0.5*Wz
    }
    ws[WS_WT + t] = v;
  } else if (t < 67584){
    // relT[l][b][j][d] = (query[b] @ rel_W[l])[j*64+d] + rel_b[l][j*64+d]
    int e = t - 49152;
    int d = e & 63; int j = (e>>6)%12; int b = (e/768)&7; int l = e/6144;
    float acc = rel_b[l*768 + j*64 + d];
    fp W = rel_W + (size_t)l*64*768 + j*64 + d;
    fp q = query + b*64;
    #pragma unroll 8
    for (int k=0;k<64;k++) acc += q[k] * W[k*768];
    ws[WS_RELT + e] = acc;
  } else if (t < 68096){
    int e = t - 67584; int b = e>>6; int j = e&63;
    float acc = mlp_b1[j];
    fp q = query + b*64;
    #pragma unroll 8
    for (int i=0;i<64;i++) acc += q[i] * mlp_W1[(64+i)*64 + j];
    ws[WS_QW1 + e] = acc;
  }
}

// blocks 0..95: (b,i0) -> Q2[b,i0,0..11]; blocks 96..103: b -> QW3[b,0..11]
__global__ void k_mid(fp indicator, fp lin_W, fp lin_b, float* ws){
  __shared__ float sC2[64], sC2W[64], sP1[64], sQ3[12][64];
  int tid = threadIdx.x;                    // 768 threads = 12 waves
  int w = tid>>6, j = tid&63;
  bool isQ2 = blockIdx.x < 96;
  int b  = isQ2 ? blockIdx.x/12 : blockIdx.x-96;
  int i0 = isQ2 ? blockIdx.x%12 : 0;
  if (w == 0){
    float acc = lin_b[j];                   // C2: layer0 const state
    #pragma unroll 8
    for (int d=0; d<64; d++) acc += 2e-3f * ws[WS_WT + ((d<<6)+j)*4 + 2];
    sC2[j] = fmaxf(acc, 0.f);               // 2e-3*Wz' == 1e-3*Wz (exact)
  } else if (w == 1 && isQ2){
    const float4* W4 = (const float4*)(ws + WS_WT);        // layer0 Wt
    const float* rel = ws + WS_RELT + (b*12+i0)*64;        // l=0
    float acc = lin_b[j];
    #pragma unroll 4
    for (int d=0; d<64; d++) acc4f(indicator[d], rel[d], W4[(d<<6)+j], acc);
    sP1[j] = fmaxf(acc, 0.f);
  }
  __syncthreads();
  if (w == 0){
    float a2 = lin_b[64+j];                 // C2W = C2 @ lin_W1[0:64] + b1
    fp W1 = lin_W + 832*64;
    #pragma unroll 8
    for (int k=0;k<64;k++) a2 += sC2[k] * W1[k*64+j];
    sC2W[j] = a2;
  }
  __syncthreads();
  const float4* W4 = (const float4*)(ws + WS_WT + 16384);  // layer1 Wt
  const float* rel = ws + WS_RELT + 6144 + (b*12+w)*64;    // l=1, idx=w
  if (isQ2){
    float acc = sC2W[j];
    #pragma unroll 4
    for (int d=0; d<64; d++) acc4f(sP1[d], rel[d], W4[(d<<6)+j], acc);
    ws[WS_Q2 + ((b*12+i0)*12+w)*64 + j] = fmaxf(acc, 0.f);
  } else {
    float acc = sC2W[j];
    #pragma unroll 4
    for (int d=0; d<64; d++) acc4f(sC2[d], rel[d], W4[(d<<6)+j], acc);
    sQ3[w][j] = fmaxf(acc, 0.f);
    __syncthreads();                        // block-uniform branch
    fp W2 = lin_W + 2*832*64;               // layer2, rows 0..63
    float a = lin_b[128+j];
    #pragma unroll 8
    for (int k=0;k<64;k++) a += sQ3[w][k]*W2[k*64+j];
    ws[WS_QW3 + (b*12+w)*64 + j] = a;
  }
}

// 864 blocks x 256 thr; wave = 4 rules (b,i0,i2 shared, i1 = i1b..i1b+3).
// Wt2 staged through LDS in 4x16KB chunks (20KB/block: R9-proven sweet spot).
__global__ __launch_bounds__(256) void k_score(fp mlp_W1, fp mlp_W2, float* ws){
  __shared__ float wt_s[4096];              // 16 KB chunk
  __shared__ float fin[4][4][64];
  int tid = threadIdx.x, w = tid>>6, j = tid&63;
  int wave = blockIdx.x*4 + w;              // 0..3455
  int b = blockIdx.x/108;                   // block-uniform (432 waves/b)
  int rem = wave%432;
  int i0 = rem/36; int t36 = rem%36;
  int i2 = t36/3;  int i1b = (t36%3)*4;
  const float4* relv = (const float4*)(ws + WS_RELT + 12288 + (b*12+i2)*64);
  const float* q2base = ws + WS_Q2 + ((b*12+i0)*12 + i1b)*64;
  const float4* q0v = (const float4*)(q2base);
  const float4* q1v = (const float4*)(q2base + 64);
  const float4* q2v = (const float4*)(q2base + 128);
  const float4* q3v = (const float4*)(q2base + 192);
  float a0 = ws[WS_QW3 + (b*12+i2)*64 + j];
  float acc0=a0, acc1=a0, acc2=a0, acc3=a0;
  const float4* Wt2 = (const float4*)(ws + WS_WT + 32768);
  for (int ch=0; ch<4; ch++){
    __syncthreads();                        // protect previous chunk
    {
      const float4* src = Wt2 + ch*1024;
      float4* dst = (float4*)wt_s;
      #pragma unroll
      for (int k=0; k<4; k++) dst[tid + k*256] = src[tid + k*256];
    }
    __syncthreads();
    #pragma unroll
    for (int dq=0; dq<4; dq++){
      int dc = ch*4 + dq;
      float4 rv = relv[dc];
      float4 qa = q0v[dc], qb = q1v[dc], qc = q2v[dc], qd = q3v[dc];
      const float4* wl = (const float4*)wt_s + dq*256 + j;
      float4 w0 = wl[0], w1 = wl[64], w2 = wl[128], w3 = wl[192];
      acc4f(qa.x, rv.x, w0, acc0); acc4f(qb.x, rv.x, w0, acc1);
      acc4f(qc.x, rv.x, w0, acc2); acc4f(qd.x, rv.x, w0, acc3);
      acc4f(qa.y, rv.y, w1, acc0); acc4f(qb.y, rv.y, w1, acc1);
      acc4f(qc.y, rv.y, w1, acc2); acc4f(qd.y, rv.y, w1, acc3);
      acc4f(qa.z, rv.z, w2, acc0); acc4f(qb.z, rv.z, w2, acc1);
      acc4f(qc.z, rv.z, w2, acc2); acc4f(qd.z, rv.z, w2, acc3);
      acc4f(qa.w, rv.w, w3, acc0); acc4f(qb.w, rv.w, w3, acc1);
      acc4f(qc.w, rv.w, w3, acc2); acc4f(qd.w, rv.w, w3, acc3);
    }
  }
  __syncthreads();
  fin[w][0][j]=fmaxf(acc0,0.f); fin[w][1][j]=fmaxf(acc1,0.f);
  fin[w][2][j]=fmaxf(acc2,0.f); fin[w][3][j]=fmaxf(acc3,0.f);
  __syncthreads();
  float qw = ws[WS_QW1 + b*64 + j];
  float w2v = mlp_W2[j];
  float h0=qw, h1=qw, h2=qw, h3=qw;
  #pragma unroll 8
  for (int i=0;i<64;i++){
    float wv = mlp_W1[i*64+j];              // rows 0..63, shared by 4 rules
    h0 += fin[w][0][i]*wv; h1 += fin[w][1][i]*wv;
    h2 += fin[w][2][i]*wv; h3 += fin[w][3][i]*wv;
  }
  float s0=fmaxf(h0,0.f)*w2v, s1=fmaxf(h1,0.f)*w2v;
  float s2=fmaxf(h2,0.f)*w2v, s3=fmaxf(h3,0.f)*w2v;
  #pragma unroll
  for (int off=32; off>0; off>>=1){
    s0 += __shfl_down(s0, off, 64); s1 += __shfl_down(s1, off, 64);
    s2 += __shfl_down(s2, off, 64); s3 += __shfl_down(s3, off, 64);
  }
  if (j == 0){
    int rbase = i0*144 + i1b*12 + i2;
    float* S = ws + WS_SCORES + b*1728 + rbase;
    S[0] = s0; S[12] = s1; S[24] = s2; S[36] = s3;
  }
}

__global__ void k_final(fp relation_emb, float* ws, float* out){
  int b = blockIdx.x, tid = threadIdx.x;           // 256 threads
  __shared__ float se[1728];
  __shared__ float red[256];
  __shared__ float pb[36][4];
  __shared__ float bins[36];
  const float* sc = ws + WS_SCORES + b*1728;
  float mx = -1e30f;
  for (int r=tid; r<1728; r+=256){ float v = sc[r]; se[r] = v; mx = fmaxf(mx, v); }
  red[tid] = mx; __syncthreads();
  for (int s=128; s>0; s>>=1){ if (tid<s) red[tid] = fmaxf(red[tid], red[tid+s]); __syncthreads(); }
  mx = red[0]; __syncthreads();
  float ts = 0.f;
  for (int r=tid; r<1728; r+=256){ float e = __expf(se[r]-mx); se[r] = e; ts += e; }
  red[tid] = ts; __syncthreads();
  for (int s=128; s>0; s>>=1){ if (tid<s) red[tid] += red[tid+s]; __syncthreads(); }
  float tot = red[0]; __syncthreads();
  if (tid < 144){                           // 4 partials per bin
    int bin = tid>>2, q = tid&3;            // bin = h*12+jj
    int h = bin/12, jj = bin%12;
    float a = 0.f;
    if (h == 0){
      const float* p = se + jj*144 + q*36;
      #pragma unroll 4
      for (int k=0;k<36;k++) a += p[k];
    } else if (h == 1){
      for (int t=q*36; t<q*36+36; t++) a += se[(t/12)*144 + jj*12 + (t%12)];
    } else {
      for (int t=q*36; t<q*36+36; t++) a += se[(t/12)*144 + (t%12)*12 + jj];
    }
    pb[bin][q] = a;
  }
  __syncthreads();
  if (tid < 36) bins[tid] = (pb[tid][0]+pb[tid][1]) + (pb[tid][2]+pb[tid][3]);
  __syncthreads();
  if (tid < 192){
    int h = tid>>6, d = tid&63;
    float acc = 0.f;
    #pragma unroll
    for (int jj=0; jj<12; jj++) acc += bins[h*12+jj] * relation_emb[jj*64+d];
    out[b*192 + tid] = acc/tot;                    // subgoals, f32
  }
  if (tid >= 192 && tid < 195){
    out[1536 + b*3 + (tid-192)] = 1.0f;            // masks = True, f32
  }
}

extern "C" void kernel_launch(void* const* d_in, const int* in_sizes, int n_in,
                              void* d_out, int out_size, void* d_ws, size_t ws_size,
                              hipStream_t stream){
  fp query        = (fp)d_in[0];
  fp relation_emb = (fp)d_in[1];
  fp indicator    = (fp)d_in[2];
  fp rel_W        = (fp)d_in[3];
  fp rel_b        = (fp)d_in[4];
  fp lin_W        = (fp)d_in[5];
  fp lin_b        = (fp)d_in[6];
  fp mlp_W1       = (fp)d_in[7];
  fp mlp_b1       = (fp)d_in[8];
  fp mlp_W2       = (fp)d_in[9];
  float* ws = (float*)d_ws;
  float* out = (float*)d_out;

  k_pre1 <<<266, 256, 0, stream>>>(lin_W, query, rel_W, rel_b, mlp_W1, mlp_b1, ws);
  k_mid  <<<104, 768, 0, stream>>>(indicator, lin_W, lin_b, ws);
  k_score<<<864, 256, 0, stream>>>(mlp_W1, mlp_W2, ws);
  k_final<<<8,   256, 0, stream>>>(relation_emb, ws, out);
}